// Round 20
// baseline (93.858 us; speedup 1.0000x reference)
//
#include <hip/hip_runtime.h>

#define BT 16384
#define DK 4096
#define NE 64
#define BM 32                 // rows per block -> grid 512 = 2 blocks/CU
#define NSTG 32               // stages of 32k per kh-slice (kh split-K 4)
#define NPROBS (BT * NE)
#define NIDX (NPROBS)
#define NWTS (NPROBS + BT * 2)

typedef __bf16 bf16x8 __attribute__((ext_vector_type(8)));
typedef float f32x16 __attribute__((ext_vector_type(16)));

__device__ __forceinline__ unsigned asu(float f) { return __builtin_bit_cast(unsigned, f); }
__device__ __forceinline__ float asf(unsigned u) { return __builtin_bit_cast(float, u); }

__device__ __forceinline__ void gl_lds16(const void* g, void* l) {
    __builtin_amdgcn_global_load_lds(
        (const __attribute__((address_space(1))) unsigned int*)g,
        (__attribute__((address_space(3))) unsigned int*)l, 16, 0, 0);
}

// Split 8 f32 into 3 bf16 planes (truncation split; residuals exact in f32).
__device__ __forceinline__ void split3(const float* xx, uint4* pl) {
    unsigned h0[8], h1[8], h2[8];
#pragma unroll
    for (int j = 0; j < 8; ++j) {
        const float xf = xx[j];
        const unsigned a0 = asu(xf) & 0xFFFF0000u;
        const float r1 = xf - asf(a0);
        const unsigned a1 = asu(r1) & 0xFFFF0000u;
        const float r2 = r1 - asf(a1);
        const unsigned a2 = asu(r2) & 0xFFFF0000u;
        h0[j] = a0; h1[j] = a1; h2[j] = a2;
    }
    pl[0] = make_uint4((h0[0] >> 16) | (h0[1] & 0xFFFF0000u), (h0[2] >> 16) | (h0[3] & 0xFFFF0000u),
                       (h0[4] >> 16) | (h0[5] & 0xFFFF0000u), (h0[6] >> 16) | (h0[7] & 0xFFFF0000u));
    pl[1] = make_uint4((h1[0] >> 16) | (h1[1] & 0xFFFF0000u), (h1[2] >> 16) | (h1[3] & 0xFFFF0000u),
                       (h1[4] >> 16) | (h1[5] & 0xFFFF0000u), (h1[6] >> 16) | (h1[7] & 0xFFFF0000u));
    pl[2] = make_uint4((h2[0] >> 16) | (h2[1] & 0xFFFF0000u), (h2[2] >> 16) | (h2[3] & 0xFFFF0000u),
                       (h2[4] >> 16) | (h2[5] & 0xFFFF0000u), (h2[6] >> 16) | (h2[7] & 0xFFFF0000u));
}

// prep: W -> 3 bf16 planes in 32x32x16 B-fragment order (validated R19).
// WF idx = kst*384 + eh*192 + p*64 + l : expert = eh*32 + (l&31),
// k = kst*16 + (l>>5)*8 + j.
__global__ __launch_bounds__(256) void w_prep(
    const float* __restrict__ W, uint4* __restrict__ WF)
{
    const int g  = blockIdx.x * 256 + threadIdx.x;
    const int e  = g >> 9;
    const int kg = g & 511;
    const float4 v0 = *(const float4*)(W + (long)e * DK + kg * 8);
    const float4 v1 = *(const float4*)(W + (long)e * DK + kg * 8 + 4);
    float xx[8] = {v0.x, v0.y, v0.z, v0.w, v1.x, v1.y, v1.z, v1.w};
    uint4 pl[3];
    split3(xx, pl);
    const int kst = kg >> 1;
    const int l   = (e & 31) | ((kg & 1) << 5);
    const int eh  = e >> 5;
#pragma unroll
    for (int p = 0; p < 3; ++p)
        WF[(long)kst * 384 + eh * 192 + p * 64 + l] = pl[p];
}

// Main: 512 blocks x 32 rows (2 blocks/CU), 8 waves = eh(2) x kh(4).
// R20 = R19 with QUEUE-DISCIPLINED issue order + counted-vmcnt barrier:
// per stage: bn -> X(s+1) -> compute0(bc) -> bc_next -> compute1(bn) ->
// s_waitcnt vmcnt(6) + s_barrier. Every wait retires exactly its own load
// group; X (older than bc_next) drains at the barrier while bc_next stays
// in flight ACROSS the barrier (register dest -> no cross-wave hazard).
__global__ __launch_bounds__(512) void token_router(
    const float* __restrict__ x, const uint4* __restrict__ WF,
    float* __restrict__ out)
{
    __shared__ float4 xs4[2 * 4 * 256];      // 32 KB: [buf][slice kh][32 rows][8 quads]
    __shared__ float  lg[BM * 68 + 2 * BM];  // 9 KB

    const int tid  = threadIdx.x;
    const int wv   = tid >> 6;
    const int lane = tid & 63;
    const int eh   = wv & 1;
    const int kh   = wv >> 1;
    const long rowbase = (long)blockIdx.x * BM;

    // staging (R19-verified): lane -> row grp*8+(l>>3), slot l&7 holds quad (l&7)^(l>>3)
    const int sr = lane >> 3, sq = lane & 7;
    const float* gxa = x + (rowbase + (wv & 3) * 8 + sr) * (long)DK
                         + (wv >> 2) * 1024 + ((sq ^ sr) << 2);
    const float* gxb = gxa + 2048;
    const int dsta = (wv >> 2) * 256 + (wv & 3) * 64 + lane;
    const int dstb = dsta + 512;

    // A-read coords: row r = lane&31 in slice kh; slot = Q ^ (r&7)
    const int rr  = lane & 31;
    const int rsw = rr & 7;
    const int xbase = kh * 256 + rr * 8;

    const uint4* wfl = WF + eh * 192 + lane;

    f32x16 acc;
#pragma unroll
    for (int i = 0; i < 16; ++i) acc[i] = 0.f;

    uint4 bc0, bc1, bc2, bn0, bn1, bn2;

    // prologue: stage X(0) -> buf0; load B(kh*64) -> current set
    gl_lds16(gxa, xs4 + dsta);
    gl_lds16(gxb, xs4 + dstb);
    {
        const long k0 = (long)(kh * 64) * 384;
        bc0 = wfl[k0]; bc1 = wfl[k0 + 64]; bc2 = wfl[k0 + 128];
    }
    __syncthreads();

#define COMPUTE(PB, T, B0r, B1r, B2r) do {                                    \
    const int qb = (T) * 4 + (lane >> 5) * 2;                                 \
    const float4 alo = xs4[(PB) + xbase + (qb ^ rsw)];                        \
    const float4 ahi = xs4[(PB) + xbase + ((qb + 1) ^ rsw)];                  \
    float xx[8] = {alo.x, alo.y, alo.z, alo.w, ahi.x, ahi.y, ahi.z, ahi.w};   \
    uint4 pl[3];                                                              \
    split3(xx, pl);                                                           \
    const bf16x8 A0 = __builtin_bit_cast(bf16x8, pl[0]);                      \
    const bf16x8 A1 = __builtin_bit_cast(bf16x8, pl[1]);                      \
    const bf16x8 A2 = __builtin_bit_cast(bf16x8, pl[2]);                      \
    const bf16x8 B0 = __builtin_bit_cast(bf16x8, B0r);                        \
    const bf16x8 B1 = __builtin_bit_cast(bf16x8, B1r);                        \
    const bf16x8 B2 = __builtin_bit_cast(bf16x8, B2r);                        \
    acc = __builtin_amdgcn_mfma_f32_32x32x16_bf16(A0, B0, acc, 0, 0, 0);      \
    acc = __builtin_amdgcn_mfma_f32_32x32x16_bf16(A0, B1, acc, 0, 0, 0);      \
    acc = __builtin_amdgcn_mfma_f32_32x32x16_bf16(A1, B0, acc, 0, 0, 0);      \
    acc = __builtin_amdgcn_mfma_f32_32x32x16_bf16(A1, B1, acc, 0, 0, 0);      \
    acc = __builtin_amdgcn_mfma_f32_32x32x16_bf16(A0, B2, acc, 0, 0, 0);      \
    acc = __builtin_amdgcn_mfma_f32_32x32x16_bf16(A2, B0, acc, 0, 0, 0);      \
} while (0)

    for (int s = 0; s < NSTG; ++s) {
        const int pb = (s & 1) * 1024;
        const int nb = pb ^ 1024;
        // (1) bn: B for substep 1 (kst 2s+1) -- oldest of this stage's loads
        {
            const long kn = ((long)(kh * 64 + s * 2 + 1)) * 384;
            bn0 = wfl[kn]; bn1 = wfl[kn + 64]; bn2 = wfl[kn + 128];
        }
        // (2) X(s+1): next in queue (older than bc_next -> drainable alone)
        if (s + 1 < NSTG) {
            gl_lds16(gxa + (s + 1) * 32, xs4 + nb + dsta);
            gl_lds16(gxb + (s + 1) * 32, xs4 + nb + dstb);
        }
        __builtin_amdgcn_sched_barrier(0);
        // (3) compute substep 0 with bc (retired by last barrier window)
        COMPUTE(pb, 0, bc0, bc1, bc2);
        // (4) bc_next: B for next stage's substep 0 (newest -> crosses barrier)
        if (s + 1 < NSTG) {
            const long kn = ((long)(kh * 64 + (s + 1) * 2)) * 384;
            bc0 = wfl[kn]; bc1 = wfl[kn + 64]; bc2 = wfl[kn + 128];
        }
        __builtin_amdgcn_sched_barrier(0);
        // (5) compute substep 1 with bn (wait retires bn only: X+bc_next newer)
        COMPUTE(pb, 1, bn0, bn1, bn2);
        // (6) counted drain: retire X (oldest), keep bc_next in flight
        __builtin_amdgcn_sched_barrier(0);
        asm volatile("s_waitcnt vmcnt(6)" ::: "memory");
        __builtin_amdgcn_s_barrier();
        __builtin_amdgcn_sched_barrier(0);
    }
#undef COMPUTE

    __syncthreads();   // full drain before combine

    // ---- split-K combine: 4 barrier-phases over kh, fixed order ----
    // C/D map (m74/m101): col = lane&31, row = (reg&3) + 8*(reg>>2) + 4*(lane>>5)
#pragma unroll
    for (int ph = 0; ph < 4; ++ph) {
        if (kh == ph) {
            const int col = eh * 32 + (lane & 31);
            const int rbase = 4 * (lane >> 5);
#pragma unroll
            for (int rg = 0; rg < 16; ++rg) {
                const int row = (rg & 3) + 8 * (rg >> 2) + rbase;
                if (ph == 0) lg[row * 68 + col]  = acc[rg];
                else         lg[row * 68 + col] += acc[rg];
            }
        }
        __syncthreads();
    }

    // ---- per-row softmax stats + stable top-2 (one thread per row) ----
    float* rowm   = lg + BM * 68;
    float* rowinv = rowm + BM;
    if (tid < BM) {
        const int row = tid;
        float m = -3.4e38f;
        for (int e = 0; e < NE; ++e) m = fmaxf(m, lg[row * 68 + e]);
        float s = 0.f;
        float v1 = -1.f, v2 = -1.f;
        int   i1 = 0,    i2 = 0;
        for (int e = 0; e < NE; ++e) {
            const float p = __expf(lg[row * 68 + e] - m);
            s += p;
            if (p > v1)      { v2 = v1; i2 = i1; v1 = p; i1 = e; }
            else if (p > v2) { v2 = p; i2 = e; }
        }
        const float inv = 1.f / s;
        rowm[row]   = m;
        rowinv[row] = inv;
        const long grow = rowbase + row;
        const float p1 = v1 * inv, p2 = v2 * inv;
        const float dn = p1 + p2 + 1e-9f;
        out[NIDX + grow * 2 + 0] = (float)i1;
        out[NIDX + grow * 2 + 1] = (float)i2;
        out[NWTS + grow * 2 + 0] = p1 / dn;
        out[NWTS + grow * 2 + 1] = p2 / dn;
    }
    __syncthreads();

    // ---- probs write: 512 threads x 1 float4, coalesced ----
    {
        const int row = tid >> 4;
        const int e0  = (tid & 15) << 2;
        const float m = rowm[row], inv = rowinv[row];
        const long grow = rowbase + row;
        const float4 l4 = *reinterpret_cast<const float4*>(&lg[row * 68 + e0]);
        float4 p;
        p.x = __expf(l4.x - m) * inv;
        p.y = __expf(l4.y - m) * inv;
        p.z = __expf(l4.z - m) * inv;
        p.w = __expf(l4.w - m) * inv;
        *reinterpret_cast<float4*>(&out[grow * (long)NE + e0]) = p;
    }
}

extern "C" void kernel_launch(void* const* d_in, const int* in_sizes, int n_in,
                              void* d_out, int out_size, void* d_ws, size_t ws_size,
                              hipStream_t stream) {
    const float* x = (const float*)d_in[0];
    const float* W = (const float*)d_in[1];
    float* out = (float*)d_out;
    uint4* WF  = (uint4*)d_ws;   // 1.5 MB fragment-ordered W planes

    w_prep<<<dim3(128), dim3(256), 0, stream>>>(W, WF);
    token_router<<<dim3(BT / BM), dim3(512), 0, stream>>>(x, WF, out);
}

// Round 21
// 89.875 us; speedup vs baseline: 1.0443x; 1.0443x over previous
//
#include <hip/hip_runtime.h>

#define BT 16384
#define DK 4096
#define NE 64
#define BM 32                 // rows per block -> grid 512 = 2 blocks/CU
#define NSTG 32               // stages of 32k per kh-slice (kh split-K 4)
#define NPROBS (BT * NE)
#define NIDX (NPROBS)
#define NWTS (NPROBS + BT * 2)

typedef __bf16 bf16x8 __attribute__((ext_vector_type(8)));
typedef float f32x16 __attribute__((ext_vector_type(16)));

__device__ __forceinline__ unsigned asu(float f) { return __builtin_bit_cast(unsigned, f); }
__device__ __forceinline__ float asf(unsigned u) { return __builtin_bit_cast(float, u); }

__device__ __forceinline__ void gl_lds16(const void* g, void* l) {
    __builtin_amdgcn_global_load_lds(
        (const __attribute__((address_space(1))) unsigned int*)g,
        (__attribute__((address_space(3))) unsigned int*)l, 16, 0, 0);
}

// Split 8 f32 into 3 bf16 planes (truncation split; residuals exact in f32).
__device__ __forceinline__ void split3(const float* xx, uint4* pl) {
    unsigned h0[8], h1[8], h2[8];
#pragma unroll
    for (int j = 0; j < 8; ++j) {
        const float xf = xx[j];
        const unsigned a0 = asu(xf) & 0xFFFF0000u;
        const float r1 = xf - asf(a0);
        const unsigned a1 = asu(r1) & 0xFFFF0000u;
        const float r2 = r1 - asf(a1);
        const unsigned a2 = asu(r2) & 0xFFFF0000u;
        h0[j] = a0; h1[j] = a1; h2[j] = a2;
    }
    pl[0] = make_uint4((h0[0] >> 16) | (h0[1] & 0xFFFF0000u), (h0[2] >> 16) | (h0[3] & 0xFFFF0000u),
                       (h0[4] >> 16) | (h0[5] & 0xFFFF0000u), (h0[6] >> 16) | (h0[7] & 0xFFFF0000u));
    pl[1] = make_uint4((h1[0] >> 16) | (h1[1] & 0xFFFF0000u), (h1[2] >> 16) | (h1[3] & 0xFFFF0000u),
                       (h1[4] >> 16) | (h1[5] & 0xFFFF0000u), (h1[6] >> 16) | (h1[7] & 0xFFFF0000u));
    pl[2] = make_uint4((h2[0] >> 16) | (h2[1] & 0xFFFF0000u), (h2[2] >> 16) | (h2[3] & 0xFFFF0000u),
                       (h2[4] >> 16) | (h2[5] & 0xFFFF0000u), (h2[6] >> 16) | (h2[7] & 0xFFFF0000u));
}

// prep: W -> 3 bf16 planes in 32x32x16 B-fragment order.
// WF idx = kst*384 + eh*192 + p*64 + l : expert = eh*32 + (l&31),
// k = kst*16 + (l>>5)*8 + j. (A uses the same (l>>5, j) k-map -> k-pairing
// is self-consistent regardless of HW's internal wiring; C/D map is the
// m74/m101-verified one.)
__global__ __launch_bounds__(256) void w_prep(
    const float* __restrict__ W, uint4* __restrict__ WF)
{
    const int g  = blockIdx.x * 256 + threadIdx.x;   // 32768 threads
    const int e  = g >> 9;
    const int kg = g & 511;                          // k-octet
    const float4 v0 = *(const float4*)(W + (long)e * DK + kg * 8);
    const float4 v1 = *(const float4*)(W + (long)e * DK + kg * 8 + 4);
    float xx[8] = {v0.x, v0.y, v0.z, v0.w, v1.x, v1.y, v1.z, v1.w};
    uint4 pl[3];
    split3(xx, pl);
    const int kst = kg >> 1;
    const int l   = (e & 31) | ((kg & 1) << 5);
    const int eh  = e >> 5;
#pragma unroll
    for (int p = 0; p < 3; ++p)
        WF[(long)kst * 384 + eh * 192 + p * 64 + l] = pl[p];
}

// Main: 512 blocks x 32 rows (2 blocks/CU), 8 waves = eh(2) x kh(4).
// Wave: 32 rows x 32 experts x 1024 k, acc = ONE f32x16.
// X: block-cooperative gload_lds staging (R17-verified swizzle), dbuf,
//    issued a full stage ahead; ONE barrier per stage.
// B: dense lane-linear VMEM from WF (L2-resident), register double-buffered,
//    issued one substep ahead. Never touches LDS.
// (R19 exact — best verified variant, 91.2 us. R20's counted-vmcnt barrier
//  measured neutral-negative; reverted.)
__global__ __launch_bounds__(512) void token_router(
    const float* __restrict__ x, const uint4* __restrict__ WF,
    float* __restrict__ out)
{
    __shared__ float4 xs4[2 * 4 * 256];      // 32 KB: [buf][slice kh][32 rows][8 quads]
    __shared__ float  lg[BM * 68 + 2 * BM];  // 9 KB

    const int tid  = threadIdx.x;
    const int wv   = tid >> 6;
    const int lane = tid & 63;
    const int eh   = wv & 1;          // expert half (32 experts)
    const int kh   = wv >> 1;         // K quarter (1024 k)
    const long rowbase = (long)blockIdx.x * BM;

    // staging: wave does insts j=wv (slice wv>>2) and j=wv+8 (slice 2+(wv>>2)),
    // row-group wv&3. lane -> row grp*8+(l>>3), slot l&7 holds quad (l&7)^(l>>3).
    const int sr = lane >> 3, sq = lane & 7;
    const float* gxa = x + (rowbase + (wv & 3) * 8 + sr) * (long)DK
                         + (wv >> 2) * 1024 + ((sq ^ sr) << 2);
    const float* gxb = gxa + 2048;           // slice +2
    const int dsta = (wv >> 2) * 256 + (wv & 3) * 64 + lane;
    const int dstb = dsta + 512;

    // A-read coords: row r = lane&31 in slice kh; slot = Q ^ (r&7)
    const int rr  = lane & 31;
    const int rsw = rr & 7;
    const int xbase = kh * 256 + rr * 8;

    // B source: kst = kh*64 + s*2 + t
    const uint4* wfl = WF + eh * 192 + lane;

    f32x16 acc;
#pragma unroll
    for (int i = 0; i < 16; ++i) acc[i] = 0.f;

    uint4 bc0, bc1, bc2, bn0, bn1, bn2;

    // prologue: stage X(0) -> buf0; load B(kh*64) -> current set
    gl_lds16(gxa, xs4 + dsta);
    gl_lds16(gxb, xs4 + dstb);
    {
        const long k0 = (long)(kh * 64) * 384;
        bc0 = wfl[k0]; bc1 = wfl[k0 + 64]; bc2 = wfl[k0 + 128];
    }
    __syncthreads();

#define COMPUTE(PB, T, B0r, B1r, B2r) do {                                    \
    const int qb = (T) * 4 + (lane >> 5) * 2;                                 \
    const float4 alo = xs4[(PB) + xbase + (qb ^ rsw)];                        \
    const float4 ahi = xs4[(PB) + xbase + ((qb + 1) ^ rsw)];                  \
    float xx[8] = {alo.x, alo.y, alo.z, alo.w, ahi.x, ahi.y, ahi.z, ahi.w};   \
    uint4 pl[3];                                                              \
    split3(xx, pl);                                                           \
    const bf16x8 A0 = __builtin_bit_cast(bf16x8, pl[0]);                      \
    const bf16x8 A1 = __builtin_bit_cast(bf16x8, pl[1]);                      \
    const bf16x8 A2 = __builtin_bit_cast(bf16x8, pl[2]);                      \
    const bf16x8 B0 = __builtin_bit_cast(bf16x8, B0r);                        \
    const bf16x8 B1 = __builtin_bit_cast(bf16x8, B1r);                        \
    const bf16x8 B2 = __builtin_bit_cast(bf16x8, B2r);                        \
    acc = __builtin_amdgcn_mfma_f32_32x32x16_bf16(A0, B0, acc, 0, 0, 0);      \
    acc = __builtin_amdgcn_mfma_f32_32x32x16_bf16(A0, B1, acc, 0, 0, 0);      \
    acc = __builtin_amdgcn_mfma_f32_32x32x16_bf16(A1, B0, acc, 0, 0, 0);      \
    acc = __builtin_amdgcn_mfma_f32_32x32x16_bf16(A1, B1, acc, 0, 0, 0);      \
    acc = __builtin_amdgcn_mfma_f32_32x32x16_bf16(A0, B2, acc, 0, 0, 0);      \
    acc = __builtin_amdgcn_mfma_f32_32x32x16_bf16(A2, B0, acc, 0, 0, 0);      \
} while (0)

    for (int s = 0; s < NSTG; ++s) {
        const int pb = (s & 1) * 1024;
        const int nb = pb ^ 1024;
        if (s + 1 < NSTG) {                  // X(s+1): full stage to land
            gl_lds16(gxa + (s + 1) * 32, xs4 + nb + dsta);
            gl_lds16(gxb + (s + 1) * 32, xs4 + nb + dstb);
        }
        // substep 0: issue B(t=1), compute with current set
        {
            const long kn = ((long)(kh * 64 + s * 2 + 1)) * 384;
            bn0 = wfl[kn]; bn1 = wfl[kn + 64]; bn2 = wfl[kn + 128];
            COMPUTE(pb, 0, bc0, bc1, bc2);
        }
        // substep 1: issue B(next stage t=0), compute with spare set
        {
            if (s + 1 < NSTG) {
                const long kn = ((long)(kh * 64 + (s + 1) * 2)) * 384;
                bc0 = wfl[kn]; bc1 = wfl[kn + 64]; bc2 = wfl[kn + 128];
            }
            COMPUTE(pb, 1, bn0, bn1, bn2);
        }
        __syncthreads();                     // single drain point per stage
    }
#undef COMPUTE

    // ---- split-K combine: 4 barrier-phases over kh, fixed order ----
    // C/D map (m74/m101): col = lane&31, row = (reg&3) + 8*(reg>>2) + 4*(lane>>5)
#pragma unroll
    for (int ph = 0; ph < 4; ++ph) {
        if (kh == ph) {
            const int col = eh * 32 + (lane & 31);
            const int rbase = 4 * (lane >> 5);
#pragma unroll
            for (int rg = 0; rg < 16; ++rg) {
                const int row = (rg & 3) + 8 * (rg >> 2) + rbase;
                if (ph == 0) lg[row * 68 + col]  = acc[rg];
                else         lg[row * 68 + col] += acc[rg];
            }
        }
        __syncthreads();
    }

    // ---- per-row softmax stats + stable top-2 (one thread per row) ----
    float* rowm   = lg + BM * 68;
    float* rowinv = rowm + BM;
    if (tid < BM) {
        const int row = tid;
        float m = -3.4e38f;
        for (int e = 0; e < NE; ++e) m = fmaxf(m, lg[row * 68 + e]);
        float s = 0.f;
        float v1 = -1.f, v2 = -1.f;
        int   i1 = 0,    i2 = 0;
        for (int e = 0; e < NE; ++e) {
            const float p = __expf(lg[row * 68 + e] - m);
            s += p;
            if (p > v1)      { v2 = v1; i2 = i1; v1 = p; i1 = e; }
            else if (p > v2) { v2 = p; i2 = e; }
        }
        const float inv = 1.f / s;
        rowm[row]   = m;
        rowinv[row] = inv;
        const long grow = rowbase + row;
        const float p1 = v1 * inv, p2 = v2 * inv;
        const float dn = p1 + p2 + 1e-9f;
        out[NIDX + grow * 2 + 0] = (float)i1;
        out[NIDX + grow * 2 + 1] = (float)i2;
        out[NWTS + grow * 2 + 0] = p1 / dn;
        out[NWTS + grow * 2 + 1] = p2 / dn;
    }
    __syncthreads();

    // ---- probs write: 512 threads x 1 float4, coalesced ----
    {
        const int row = tid >> 4;
        const int e0  = (tid & 15) << 2;
        const float m = rowm[row], inv = rowinv[row];
        const long grow = rowbase + row;
        const float4 l4 = *reinterpret_cast<const float4*>(&lg[row * 68 + e0]);
        float4 p;
        p.x = __expf(l4.x - m) * inv;
        p.y = __expf(l4.y - m) * inv;
        p.z = __expf(l4.z - m) * inv;
        p.w = __expf(l4.w - m) * inv;
        *reinterpret_cast<float4*>(&out[grow * (long)NE + e0]) = p;
    }
}

extern "C" void kernel_launch(void* const* d_in, const int* in_sizes, int n_in,
                              void* d_out, int out_size, void* d_ws, size_t ws_size,
                              hipStream_t stream) {
    const float* x = (const float*)d_in[0];
    const float* W = (const float*)d_in[1];
    float* out = (float*)d_out;
    uint4* WF  = (uint4*)d_ws;   // 1.5 MB fragment-ordered W planes (32-wide tiles)

    w_prep<<<dim3(128), dim3(256), 0, stream>>>(W, WF);
    token_router<<<dim3(BT / BM), dim3(512), 0, stream>>>(x, WF, out);
}

// Round 22
// 89.796 us; speedup vs baseline: 1.0452x; 1.0009x over previous
//
#include <hip/hip_runtime.h>

#define BT 16384
#define DK 4096
#define NE 64
#define BM 32                 // rows per block -> grid 512 = 2 blocks/CU
#define NSTG 16               // stages of 64k per kh-slice (kh split-K 4)
#define NPROBS (BT * NE)
#define NIDX (NPROBS)
#define NWTS (NPROBS + BT * 2)

typedef __bf16 bf16x8 __attribute__((ext_vector_type(8)));
typedef float f32x16 __attribute__((ext_vector_type(16)));

__device__ __forceinline__ unsigned asu(float f) { return __builtin_bit_cast(unsigned, f); }
__device__ __forceinline__ float asf(unsigned u) { return __builtin_bit_cast(float, u); }

__device__ __forceinline__ void gl_lds16(const void* g, void* l) {
    __builtin_amdgcn_global_load_lds(
        (const __attribute__((address_space(1))) unsigned int*)g,
        (__attribute__((address_space(3))) unsigned int*)l, 16, 0, 0);
}

// Split 8 f32 into 3 bf16 planes (truncation split; residuals exact in f32).
__device__ __forceinline__ void split3(const float* xx, uint4* pl) {
    unsigned h0[8], h1[8], h2[8];
#pragma unroll
    for (int j = 0; j < 8; ++j) {
        const float xf = xx[j];
        const unsigned a0 = asu(xf) & 0xFFFF0000u;
        const float r1 = xf - asf(a0);
        const unsigned a1 = asu(r1) & 0xFFFF0000u;
        const float r2 = r1 - asf(a1);
        const unsigned a2 = asu(r2) & 0xFFFF0000u;
        h0[j] = a0; h1[j] = a1; h2[j] = a2;
    }
    pl[0] = make_uint4((h0[0] >> 16) | (h0[1] & 0xFFFF0000u), (h0[2] >> 16) | (h0[3] & 0xFFFF0000u),
                       (h0[4] >> 16) | (h0[5] & 0xFFFF0000u), (h0[6] >> 16) | (h0[7] & 0xFFFF0000u));
    pl[1] = make_uint4((h1[0] >> 16) | (h1[1] & 0xFFFF0000u), (h1[2] >> 16) | (h1[3] & 0xFFFF0000u),
                       (h1[4] >> 16) | (h1[5] & 0xFFFF0000u), (h1[6] >> 16) | (h1[7] & 0xFFFF0000u));
    pl[2] = make_uint4((h2[0] >> 16) | (h2[1] & 0xFFFF0000u), (h2[2] >> 16) | (h2[3] & 0xFFFF0000u),
                       (h2[4] >> 16) | (h2[5] & 0xFFFF0000u), (h2[6] >> 16) | (h2[7] & 0xFFFF0000u));
}

// prep: W -> 3 bf16 planes in 32x32x16 B-fragment order (validated R19/R21).
// WF idx = kst*384 + eh*192 + p*64 + l : expert = eh*32 + (l&31),
// k = kst*16 + (l>>5)*8 + j.
__global__ __launch_bounds__(256) void w_prep(
    const float* __restrict__ W, uint4* __restrict__ WF)
{
    const int g  = blockIdx.x * 256 + threadIdx.x;
    const int e  = g >> 9;
    const int kg = g & 511;
    const float4 v0 = *(const float4*)(W + (long)e * DK + kg * 8);
    const float4 v1 = *(const float4*)(W + (long)e * DK + kg * 8 + 4);
    float xx[8] = {v0.x, v0.y, v0.z, v0.w, v1.x, v1.y, v1.z, v1.w};
    uint4 pl[3];
    split3(xx, pl);
    const int kst = kg >> 1;
    const int l   = (e & 31) | ((kg & 1) << 5);
    const int eh  = e >> 5;
#pragma unroll
    for (int p = 0; p < 3; ++p)
        WF[(long)kst * 384 + eh * 192 + p * 64 + l] = pl[p];
}

// Main: 512 blocks x 32 rows (2 blocks/CU), 8 waves = eh(2) x kh(4).
// R22 = R19 with HALVED BARRIER COUNT: 16 stages of 64k (4 substeps), X tile
// 64 KB dbuf. LDS layout gains a k-half dim so gload_lds dests stay
// lane-linear: [buf][slice 4][khalf 2][row 32][quad 8]. B cadence unchanged
// (register sets alternate, issued one substep ahead).
__global__ __launch_bounds__(512) void token_router(
    const float* __restrict__ x, const uint4* __restrict__ WF,
    float* __restrict__ out)
{
    __shared__ float4 xs4[2 * 2048];         // 64 KB X, double-buffered
    __shared__ float  lg[BM * 68 + 2 * BM];  // 9 KB

    const int tid  = threadIdx.x;
    const int wv   = tid >> 6;
    const int lane = tid & 63;
    const int eh   = wv & 1;          // expert half (32 experts)
    const int kh   = wv >> 1;         // K quarter (1024 k)
    const long rowbase = (long)blockIdx.x * BM;

    // staging: wave wv handles row-group g=wv&3 for slices a=wv>>2 and b=2+a,
    // each slice in 2 k-halves. lane: row g*8+(l>>3), slot l&7 holds global
    // quad (l&7)^(l>>3) within the k-half (pre-swizzled source).
    const int sr = lane >> 3, sq = lane & 7;
    const float* gxa = x + (rowbase + (wv & 3) * 8 + sr) * (long)DK
                         + (wv >> 2) * 1024 + ((sq ^ sr) << 2);
    const float* gxb = gxa + 2048;           // slice +2
    const int d0 = (wv >> 2) * 512 + (wv & 3) * 64 + lane;   // slice a, h=0
    const int d1 = d0 + 256;                                  // slice a, h=1
    const int d2 = d0 + 1024;                                 // slice b, h=0
    const int d3 = d2 + 256;                                  // slice b, h=1

    // A-read coords: row rr in slice kh; [slice][khalf][row][quad8]
    const int rr  = lane & 31;
    const int rsw = rr & 7;
    const int xbase = kh * 512 + rr * 8;

    const uint4* wfl = WF + eh * 192 + lane;

    f32x16 acc;
#pragma unroll
    for (int i = 0; i < 16; ++i) acc[i] = 0.f;

    uint4 bc0, bc1, bc2, bn0, bn1, bn2;

    // prologue: stage X(0) -> buf0; load B(kst = kh*64) -> current set
    gl_lds16(gxa,      xs4 + d0);
    gl_lds16(gxa + 32, xs4 + d1);
    gl_lds16(gxb,      xs4 + d2);
    gl_lds16(gxb + 32, xs4 + d3);
    {
        const long k0 = (long)(kh * 64) * 384;
        bc0 = wfl[k0]; bc1 = wfl[k0 + 64]; bc2 = wfl[k0 + 128];
    }
    __syncthreads();

#define COMPUTE(PB, T, B0r, B1r, B2r) do {                                    \
    const int qb = ((T) & 1) * 4 + (lane >> 5) * 2;                           \
    const int hb = ((T) >> 1) * 256;                                          \
    const float4 alo = xs4[(PB) + xbase + hb + (qb ^ rsw)];                   \
    const float4 ahi = xs4[(PB) + xbase + hb + ((qb + 1) ^ rsw)];             \
    float xx[8] = {alo.x, alo.y, alo.z, alo.w, ahi.x, ahi.y, ahi.z, ahi.w};   \
    uint4 pl[3];                                                              \
    split3(xx, pl);                                                           \
    const bf16x8 A0 = __builtin_bit_cast(bf16x8, pl[0]);                      \
    const bf16x8 A1 = __builtin_bit_cast(bf16x8, pl[1]);                      \
    const bf16x8 A2 = __builtin_bit_cast(bf16x8, pl[2]);                      \
    const bf16x8 B0 = __builtin_bit_cast(bf16x8, B0r);                        \
    const bf16x8 B1 = __builtin_bit_cast(bf16x8, B1r);                        \
    const bf16x8 B2 = __builtin_bit_cast(bf16x8, B2r);                        \
    acc = __builtin_amdgcn_mfma_f32_32x32x16_bf16(A0, B0, acc, 0, 0, 0);      \
    acc = __builtin_amdgcn_mfma_f32_32x32x16_bf16(A0, B1, acc, 0, 0, 0);      \
    acc = __builtin_amdgcn_mfma_f32_32x32x16_bf16(A1, B0, acc, 0, 0, 0);      \
    acc = __builtin_amdgcn_mfma_f32_32x32x16_bf16(A1, B1, acc, 0, 0, 0);      \
    acc = __builtin_amdgcn_mfma_f32_32x32x16_bf16(A0, B2, acc, 0, 0, 0);      \
    acc = __builtin_amdgcn_mfma_f32_32x32x16_bf16(A2, B0, acc, 0, 0, 0);      \
} while (0)

    for (int s = 0; s < NSTG; ++s) {
        const int pb = (s & 1) * 2048;
        const int nb = pb ^ 2048;
        const int kbase = kh * 64 + s * 4;
        if (s + 1 < NSTG) {                  // X(s+1): full stage to land
            gl_lds16(gxa + (s + 1) * 64,      xs4 + nb + d0);
            gl_lds16(gxa + (s + 1) * 64 + 32, xs4 + nb + d1);
            gl_lds16(gxb + (s + 1) * 64,      xs4 + nb + d2);
            gl_lds16(gxb + (s + 1) * 64 + 32, xs4 + nb + d3);
        }
        // substep 0: issue B(T=1), compute T=0 with bc
        {
            const long kn = (long)(kbase + 1) * 384;
            bn0 = wfl[kn]; bn1 = wfl[kn + 64]; bn2 = wfl[kn + 128];
            COMPUTE(pb, 0, bc0, bc1, bc2);
        }
        // substep 1: issue B(T=2), compute T=1 with bn
        {
            const long kn = (long)(kbase + 2) * 384;
            bc0 = wfl[kn]; bc1 = wfl[kn + 64]; bc2 = wfl[kn + 128];
            COMPUTE(pb, 1, bn0, bn1, bn2);
        }
        // substep 2: issue B(T=3), compute T=2 with bc
        {
            const long kn = (long)(kbase + 3) * 384;
            bn0 = wfl[kn]; bn1 = wfl[kn + 64]; bn2 = wfl[kn + 128];
            COMPUTE(pb, 2, bc0, bc1, bc2);
        }
        // substep 3: issue B(next stage T=0), compute T=3 with bn
        {
            if (s + 1 < NSTG) {
                const long kn = (long)(kbase + 4) * 384;
                bc0 = wfl[kn]; bc1 = wfl[kn + 64]; bc2 = wfl[kn + 128];
            }
            COMPUTE(pb, 3, bn0, bn1, bn2);
        }
        __syncthreads();                     // single drain point per stage
    }
#undef COMPUTE

    // ---- split-K combine: 4 barrier-phases over kh, fixed order ----
    // C/D map (m74/m101): col = lane&31, row = (reg&3) + 8*(reg>>2) + 4*(lane>>5)
#pragma unroll
    for (int ph = 0; ph < 4; ++ph) {
        if (kh == ph) {
            const int col = eh * 32 + (lane & 31);
            const int rbase = 4 * (lane >> 5);
#pragma unroll
            for (int rg = 0; rg < 16; ++rg) {
                const int row = (rg & 3) + 8 * (rg >> 2) + rbase;
                if (ph == 0) lg[row * 68 + col]  = acc[rg];
                else         lg[row * 68 + col] += acc[rg];
            }
        }
        __syncthreads();
    }

    // ---- per-row softmax stats + stable top-2 (one thread per row) ----
    float* rowm   = lg + BM * 68;
    float* rowinv = rowm + BM;
    if (tid < BM) {
        const int row = tid;
        float m = -3.4e38f;
        for (int e = 0; e < NE; ++e) m = fmaxf(m, lg[row * 68 + e]);
        float s = 0.f;
        float v1 = -1.f, v2 = -1.f;
        int   i1 = 0,    i2 = 0;
        for (int e = 0; e < NE; ++e) {
            const float p = __expf(lg[row * 68 + e] - m);
            s += p;
            if (p > v1)      { v2 = v1; i2 = i1; v1 = p; i1 = e; }
            else if (p > v2) { v2 = p; i2 = e; }
        }
        const float inv = 1.f / s;
        rowm[row]   = m;
        rowinv[row] = inv;
        const long grow = rowbase + row;
        const float p1 = v1 * inv, p2 = v2 * inv;
        const float dn = p1 + p2 + 1e-9f;
        out[NIDX + grow * 2 + 0] = (float)i1;
        out[NIDX + grow * 2 + 1] = (float)i2;
        out[NWTS + grow * 2 + 0] = p1 / dn;
        out[NWTS + grow * 2 + 1] = p2 / dn;
    }
    __syncthreads();

    // ---- probs write: 512 threads x 1 float4, coalesced ----
    {
        const int row = tid >> 4;
        const int e0  = (tid & 15) << 2;
        const float m = rowm[row], inv = rowinv[row];
        const long grow = rowbase + row;
        const float4 l4 = *reinterpret_cast<const float4*>(&lg[row * 68 + e0]);
        float4 p;
        p.x = __expf(l4.x - m) * inv;
        p.y = __expf(l4.y - m) * inv;
        p.z = __expf(l4.z - m) * inv;
        p.w = __expf(l4.w - m) * inv;
        *reinterpret_cast<float4*>(&out[grow * (long)NE + e0]) = p;
    }
}

extern "C" void kernel_launch(void* const* d_in, const int* in_sizes, int n_in,
                              void* d_out, int out_size, void* d_ws, size_t ws_size,
                              hipStream_t stream) {
    const float* x = (const float*)d_in[0];
    const float* W = (const float*)d_in[1];
    float* out = (float*)d_out;
    uint4* WF  = (uint4*)d_ws;   // 1.5 MB fragment-ordered W planes

    w_prep<<<dim3(128), dim3(256), 0, stream>>>(W, WF);
    token_router<<<dim3(BT / BM), dim3(512), 0, stream>>>(x, WF, out);
}

// Round 23
// 86.992 us; speedup vs baseline: 1.0789x; 1.0322x over previous
//
#include <hip/hip_runtime.h>

#define BT 16384
#define DK 4096
#define NE 64
#define BM 64                 // rows per block -> grid 256
#define NSTG 16               // stages of 32k per kh-slice (kh split-K 8)
#define NPROBS (BT * NE)
#define NIDX (NPROBS)
#define NWTS (NPROBS + BT * 2)

typedef __bf16 bf16x8 __attribute__((ext_vector_type(8)));
typedef float f32x16 __attribute__((ext_vector_type(16)));

__device__ __forceinline__ unsigned asu(float f) { return __builtin_bit_cast(unsigned, f); }
__device__ __forceinline__ float asf(unsigned u) { return __builtin_bit_cast(float, u); }

__device__ __forceinline__ void gl_lds16(const void* g, void* l) {
    __builtin_amdgcn_global_load_lds(
        (const __attribute__((address_space(1))) unsigned int*)g,
        (__attribute__((address_space(3))) unsigned int*)l, 16, 0, 0);
}

// Split 8 f32 into 3 bf16 planes (truncation split; residuals exact in f32).
__device__ __forceinline__ void split3(const float* xx, uint4* pl) {
    unsigned h0[8], h1[8], h2[8];
#pragma unroll
    for (int j = 0; j < 8; ++j) {
        const float xf = xx[j];
        const unsigned a0 = asu(xf) & 0xFFFF0000u;
        const float r1 = xf - asf(a0);
        const unsigned a1 = asu(r1) & 0xFFFF0000u;
        const float r2 = r1 - asf(a1);
        const unsigned a2 = asu(r2) & 0xFFFF0000u;
        h0[j] = a0; h1[j] = a1; h2[j] = a2;
    }
    pl[0] = make_uint4((h0[0] >> 16) | (h0[1] & 0xFFFF0000u), (h0[2] >> 16) | (h0[3] & 0xFFFF0000u),
                       (h0[4] >> 16) | (h0[5] & 0xFFFF0000u), (h0[6] >> 16) | (h0[7] & 0xFFFF0000u));
    pl[1] = make_uint4((h1[0] >> 16) | (h1[1] & 0xFFFF0000u), (h1[2] >> 16) | (h1[3] & 0xFFFF0000u),
                       (h1[4] >> 16) | (h1[5] & 0xFFFF0000u), (h1[6] >> 16) | (h1[7] & 0xFFFF0000u));
    pl[2] = make_uint4((h2[0] >> 16) | (h2[1] & 0xFFFF0000u), (h2[2] >> 16) | (h2[3] & 0xFFFF0000u),
                       (h2[4] >> 16) | (h2[5] & 0xFFFF0000u), (h2[6] >> 16) | (h2[7] & 0xFFFF0000u));
}

// prep: W -> 3 bf16 planes in 32x32x16 B-fragment order (validated R19-R22).
// WF idx = kst*384 + eh*192 + p*64 + l : expert = eh*32 + (l&31),
// k = kst*16 + (l>>5)*8 + j.
__global__ __launch_bounds__(256) void w_prep(
    const float* __restrict__ W, uint4* __restrict__ WF)
{
    const int g  = blockIdx.x * 256 + threadIdx.x;
    const int e  = g >> 9;
    const int kg = g & 511;
    const float4 v0 = *(const float4*)(W + (long)e * DK + kg * 8);
    const float4 v1 = *(const float4*)(W + (long)e * DK + kg * 8 + 4);
    float xx[8] = {v0.x, v0.y, v0.z, v0.w, v1.x, v1.y, v1.z, v1.w};
    uint4 pl[3];
    split3(xx, pl);
    const int kst = kg >> 1;
    const int l   = (e & 31) | ((kg & 1) << 5);
    const int eh  = e >> 5;
#pragma unroll
    for (int p = 0; p < 3; ++p)
        WF[(long)kst * 384 + eh * 192 + p * 64 + l] = pl[p];
}

// Main: 256 blocks x 64 rows, 1024 threads, 16 waves = eh(2) x kh(8).
// R23 = R22 cadence with HALVED B TRAFFIC: wave owns 64 rows x 32 experts x
// 512 k -> every (kst,eh) B fragment is loaded by exactly ONE wave and feeds
// 12 MFMAs (805 -> 402 MB L2). Waves/CU unchanged (16). X: gload_lds staging,
// pre-swizzled source, lane-linear dest, 128 KB dbuf; lg OVERLAID on the X
// buffer after the K-loop. B: reg-dbuf'd lane-linear VMEM (as R19-R22).
__global__ __launch_bounds__(1024) void token_router(
    const float* __restrict__ x, const uint4* __restrict__ WF,
    float* __restrict__ out)
{
    __shared__ float4 xs4[2 * 4096];         // 128 KB: [buf][slice 8][row 64][quad 8]
    __shared__ float  rowm[BM], rowinv[BM];

    const int tid  = threadIdx.x;
    const int wv   = tid >> 6;               // 0..15
    const int lane = tid & 63;
    const int eh   = wv & 1;                 // expert half (32 experts)
    const int kh   = wv >> 1;                // K eighth (512 k)
    const long rowbase = (long)blockIdx.x * BM;

    // ---- X staging: wave stages 4 units u=wv*4+i; unit = (slice u>>3,
    // row-group u&7). lane: row = rg*8+(lane>>3); slot sq=lane&7 holds global
    // quad sq^(lane>>3) (pre-swizzled source, lane-linear dest). ----
    const int sr = lane >> 3, sq = lane & 7;
    const float* gx[4];
    int dst[4];
#pragma unroll
    for (int i = 0; i < 4; ++i) {
        const int u  = wv * 4 + i;
        const int sl = u >> 3;
        const int rg = u & 7;
        gx[i]  = x + (rowbase + rg * 8 + sr) * (long)DK + sl * 512 + ((sq ^ sr) << 2);
        dst[i] = sl * 512 + rg * 64 + lane;
    }

    // A-read coords: slice kh, rows rlo=lane&31 (accL) and rlo+32 (accH)
    const int rlo  = lane & 31;
    const int rsw  = rlo & 7;
    const int baseL = kh * 512 + rlo * 8;    // + buf + slot
    const int baseH = baseL + 256;

    // B source: kst = kh*32 + s*2 + T
    const uint4* wfl = WF + eh * 192 + lane;

    f32x16 accL, accH;
#pragma unroll
    for (int i = 0; i < 16; ++i) { accL[i] = 0.f; accH[i] = 0.f; }

    uint4 bc0, bc1, bc2, bn0, bn1, bn2;

    // prologue: stage X(0) -> buf0; load B(kh*32) -> current set
#pragma unroll
    for (int i = 0; i < 4; ++i)
        gl_lds16(gx[i], xs4 + dst[i]);
    {
        const long k0 = (long)(kh * 32) * 384;
        bc0 = wfl[k0]; bc1 = wfl[k0 + 64]; bc2 = wfl[k0 + 128];
    }
    __syncthreads();

#define COMPUTE2(PB, T, B0r, B1r, B2r) do {                                   \
    const int qb = (T) * 4 + (lane >> 5) * 2;                                 \
    const float4 aloL = xs4[(PB) + baseL + (qb ^ rsw)];                       \
    const float4 ahiL = xs4[(PB) + baseL + ((qb + 1) ^ rsw)];                 \
    const float4 aloH = xs4[(PB) + baseH + (qb ^ rsw)];                       \
    const float4 ahiH = xs4[(PB) + baseH + ((qb + 1) ^ rsw)];                 \
    float xxL[8] = {aloL.x, aloL.y, aloL.z, aloL.w, ahiL.x, ahiL.y, ahiL.z, ahiL.w}; \
    float xxH[8] = {aloH.x, aloH.y, aloH.z, aloH.w, ahiH.x, ahiH.y, ahiH.z, ahiH.w}; \
    uint4 plL[3], plH[3];                                                     \
    split3(xxL, plL);                                                         \
    split3(xxH, plH);                                                         \
    const bf16x8 AL0 = __builtin_bit_cast(bf16x8, plL[0]);                    \
    const bf16x8 AL1 = __builtin_bit_cast(bf16x8, plL[1]);                    \
    const bf16x8 AL2 = __builtin_bit_cast(bf16x8, plL[2]);                    \
    const bf16x8 AH0 = __builtin_bit_cast(bf16x8, plH[0]);                    \
    const bf16x8 AH1 = __builtin_bit_cast(bf16x8, plH[1]);                    \
    const bf16x8 AH2 = __builtin_bit_cast(bf16x8, plH[2]);                    \
    const bf16x8 B0 = __builtin_bit_cast(bf16x8, B0r);                        \
    const bf16x8 B1 = __builtin_bit_cast(bf16x8, B1r);                        \
    const bf16x8 B2 = __builtin_bit_cast(bf16x8, B2r);                        \
    accL = __builtin_amdgcn_mfma_f32_32x32x16_bf16(AL0, B0, accL, 0, 0, 0);   \
    accL = __builtin_amdgcn_mfma_f32_32x32x16_bf16(AL0, B1, accL, 0, 0, 0);   \
    accL = __builtin_amdgcn_mfma_f32_32x32x16_bf16(AL1, B0, accL, 0, 0, 0);   \
    accL = __builtin_amdgcn_mfma_f32_32x32x16_bf16(AL1, B1, accL, 0, 0, 0);   \
    accL = __builtin_amdgcn_mfma_f32_32x32x16_bf16(AL0, B2, accL, 0, 0, 0);   \
    accL = __builtin_amdgcn_mfma_f32_32x32x16_bf16(AL2, B0, accL, 0, 0, 0);   \
    accH = __builtin_amdgcn_mfma_f32_32x32x16_bf16(AH0, B0, accH, 0, 0, 0);   \
    accH = __builtin_amdgcn_mfma_f32_32x32x16_bf16(AH0, B1, accH, 0, 0, 0);   \
    accH = __builtin_amdgcn_mfma_f32_32x32x16_bf16(AH1, B0, accH, 0, 0, 0);   \
    accH = __builtin_amdgcn_mfma_f32_32x32x16_bf16(AH1, B1, accH, 0, 0, 0);   \
    accH = __builtin_amdgcn_mfma_f32_32x32x16_bf16(AH0, B2, accH, 0, 0, 0);   \
    accH = __builtin_amdgcn_mfma_f32_32x32x16_bf16(AH2, B0, accH, 0, 0, 0);   \
} while (0)

    for (int s = 0; s < NSTG; ++s) {
        const int pb = (s & 1) * 4096;
        const int nb = pb ^ 4096;
        if (s + 1 < NSTG) {                  // X(s+1): full stage to land
#pragma unroll
            for (int i = 0; i < 4; ++i)
                gl_lds16(gx[i] + (s + 1) * 32, xs4 + nb + dst[i]);
        }
        // substep 0: issue B(T=1), compute with current set
        {
            const long kn = ((long)(kh * 32 + s * 2 + 1)) * 384;
            bn0 = wfl[kn]; bn1 = wfl[kn + 64]; bn2 = wfl[kn + 128];
            COMPUTE2(pb, 0, bc0, bc1, bc2);
        }
        // substep 1: issue B(next stage T=0), compute with spare set
        {
            if (s + 1 < NSTG) {
                const long kn = ((long)(kh * 32 + (s + 1) * 2)) * 384;
                bc0 = wfl[kn]; bc1 = wfl[kn + 64]; bc2 = wfl[kn + 128];
            }
            COMPUTE2(pb, 1, bn0, bn1, bn2);
        }
        __syncthreads();                     // single drain point per stage
    }
#undef COMPUTE2

    // ---- lg OVERLAYS xs4 (K-loop fully drained by the last barrier) ----
    float* lg = (float*)xs4;                 // 64 x 68 floats = 17.4 KB

    // split-K combine: 8 barrier-phases over kh, fixed order (deterministic).
    // C/D map (m74/m101): col = lane&31, row = (reg&3)+8*(reg>>2)+4*(lane>>5)
#pragma unroll
    for (int ph = 0; ph < 8; ++ph) {
        if (kh == ph) {
            const int col = eh * 32 + (lane & 31);
            const int rbase = 4 * (lane >> 5);
#pragma unroll
            for (int rg = 0; rg < 16; ++rg) {
                const int row = (rg & 3) + 8 * (rg >> 2) + rbase;
                if (ph == 0) {
                    lg[row * 68 + col]        = accL[rg];
                    lg[(row + 32) * 68 + col] = accH[rg];
                } else {
                    lg[row * 68 + col]        += accL[rg];
                    lg[(row + 32) * 68 + col] += accH[rg];
                }
            }
        }
        __syncthreads();
    }

    // ---- per-row softmax stats + stable top-2 (one thread per row) ----
    if (tid < BM) {
        const int row = tid;
        float m = -3.4e38f;
        for (int e = 0; e < NE; ++e) m = fmaxf(m, lg[row * 68 + e]);
        float s = 0.f;
        float v1 = -1.f, v2 = -1.f;
        int   i1 = 0,    i2 = 0;
        for (int e = 0; e < NE; ++e) {
            const float p = __expf(lg[row * 68 + e] - m);
            s += p;
            if (p > v1)      { v2 = v1; i2 = i1; v1 = p; i1 = e; }
            else if (p > v2) { v2 = p; i2 = e; }
        }
        const float inv = 1.f / s;
        rowm[row]   = m;
        rowinv[row] = inv;
        const long grow = rowbase + row;
        const float p1 = v1 * inv, p2 = v2 * inv;
        const float dn = p1 + p2 + 1e-9f;
        out[NIDX + grow * 2 + 0] = (float)i1;
        out[NIDX + grow * 2 + 1] = (float)i2;
        out[NWTS + grow * 2 + 0] = p1 / dn;
        out[NWTS + grow * 2 + 1] = p2 / dn;
    }
    __syncthreads();

    // ---- probs write: 1024 threads x 1 float4, coalesced ----
    {
        const int row = tid >> 4;
        const int e0  = (tid & 15) << 2;
        const float m = rowm[row], inv = rowinv[row];
        const long grow = rowbase + row;
        const float4 l4 = *reinterpret_cast<const float4*>(&lg[row * 68 + e0]);
        float4 p;
        p.x = __expf(l4.x - m) * inv;
        p.y = __expf(l4.y - m) * inv;
        p.z = __expf(l4.z - m) * inv;
        p.w = __expf(l4.w - m) * inv;
        *reinterpret_cast<float4*>(&out[grow * (long)NE + e0]) = p;
    }
}

extern "C" void kernel_launch(void* const* d_in, const int* in_sizes, int n_in,
                              void* d_out, int out_size, void* d_ws, size_t ws_size,
                              hipStream_t stream) {
    const float* x = (const float*)d_in[0];
    const float* W = (const float*)d_in[1];
    float* out = (float*)d_out;
    uint4* WF  = (uint4*)d_ws;   // 1.5 MB fragment-ordered W planes

    w_prep<<<dim3(128), dim3(256), 0, stream>>>(W, WF);
    token_router<<<dim3(BT / BM), dim3(1024), 0, stream>>>(x, WF, out);
}